// Round 7
// baseline (617.744 us; speedup 1.0000x reference)
//
#include <hip/hip_runtime.h>
#include <hip/hip_bf16.h>

typedef __bf16 bf16x8 __attribute__((ext_vector_type(8)));
typedef float  f32x4  __attribute__((ext_vector_type(4)));

#define GAS __attribute__((address_space(1)))
#define LAS __attribute__((address_space(3)))

__device__ __forceinline__ unsigned short f2bf(float f) {
    __hip_bfloat16 h = __float2bfloat16(f);
    return *reinterpret_cast<unsigned short*>(&h);
}
__device__ __forceinline__ float bf2f(unsigned short u) {
    __hip_bfloat16 h;
    *reinterpret_cast<unsigned short*>(&h) = u;
    return __bfloat162float(h);
}
__device__ __forceinline__ void storeval(float* p, float v) { *p = v; }
__device__ __forceinline__ void storeval(unsigned short* p, float v) { *p = f2bf(v); }

// ---------------------------------------------------------------------------
// prep: f32 -> bf16 bulk convert (vectorized)
// ---------------------------------------------------------------------------
__global__ void prep_x_kernel(const float* __restrict__ in, unsigned short* __restrict__ out, int total) {
    int idx = (blockIdx.x * 256 + threadIdx.x) * 4;
    if (idx >= total) return;
    float4 v = *reinterpret_cast<const float4*>(in + idx);
    ushort4 o;
    o.x = f2bf(v.x); o.y = f2bf(v.y); o.z = f2bf(v.z); o.w = f2bf(v.w);
    *reinterpret_cast<ushort4*>(out + idx) = o;
}

// ---------------------------------------------------------------------------
// prep: W[k][ci][co] f32 -> Wp[k][h][co][c8*8+j] bf16 (BK=64 halves,
// XOR-swizzled at 16B-chunk granularity — round-3-verified layout)
// ---------------------------------------------------------------------------
__global__ void prep_w_kernel(const float* __restrict__ W, unsigned short* __restrict__ Wp) {
    int idx = blockIdx.x * 256 + threadIdx.x;   // < 27*16384
    int k  = idx >> 14;
    int r  = idx & 16383;
    int h  = r >> 13;
    int rr = r & 8191;
    int co = rr >> 6;
    int cc = rr & 63;
    int c8 = cc >> 3, j = cc & 7;
    int ci = (h << 6) | ((c8 ^ (co & 7)) << 3) | j;
    Wp[idx] = f2bf(W[(k << 14) + ci * 128 + co]);
}

// ---------------------------------------------------------------------------
// FiLM: e[b][j] = emb[b] . Wt[:,j] + bt[j]. One wave per output element.
// ---------------------------------------------------------------------------
__global__ void film_kernel(const float* __restrict__ emb, const float* __restrict__ Wt,
                            const float* __restrict__ bt, float* __restrict__ e) {
    int gw = blockIdx.x * 4 + (threadIdx.x >> 6);   // 0..2047
    int lane = threadIdx.x & 63;
    int b = gw >> 8, j = gw & 255;
    float a = 0.f;
    for (int i = lane; i < 512; i += 64) a += emb[b * 512 + i] * Wt[i * 256 + j];
#pragma unroll
    for (int off = 32; off; off >>= 1) a += __shfl_xor(a, off);
    if (lane == 0) e[gw] = a + bt[j];
}

// ---------------------------------------------------------------------------
// Gather-GEMM sparse conv, BM=256, A-in-registers (bf16 table, uint4 loads),
// B in double-buffered LDS. 4 waves; wave owns 64 rows x 128 cols.
// Fused instance-norm stats epilogue. (Structure identical to round 5;
// only the A dtype changed fp8->bf16 — bisect round.)
// ---------------------------------------------------------------------------
template <typename OUT_T>
__global__ __launch_bounds__(256, 2) void conv_kernel(
        const unsigned short* __restrict__ X,    // [N][128] bf16
        const int* __restrict__ nbr,             // [N][27]
        const unsigned short* __restrict__ Wp,   // [27][2][128][64] bf16 pre-swizzled
        OUT_T* __restrict__ out,
        const int* __restrict__ bidx,
        float* __restrict__ gsum, float* __restrict__ gsq, float* __restrict__ gcnt,
        int N) {
    __shared__ __align__(16) unsigned short Bs[2][128 * 64];
    __shared__ int nbrS[256 * 27];
    __shared__ float ssum[2][128];
    __shared__ float ssq[2][128];
    __shared__ float shi;

    const int t = threadIdx.x;
    const int lane = t & 63;
    const int wave = t >> 6;
    const int n0 = blockIdx.x * 256;
    const int l15 = lane & 15, l4 = lane >> 4;

    for (int i = t; i < 256 * 27; i += 256) nbrS[i] = nbr[(size_t)n0 * 27 + i];
    if (t < 128) { ssum[0][t] = 0.f; ssum[1][t] = 0.f; ssq[0][t] = 0.f; ssq[1][t] = 0.f; }
    if (t == 0) shi = 0.f;

    f32x4 acc[4][8];
#pragma unroll
    for (int mi = 0; mi < 4; mi++)
#pragma unroll
        for (int ni = 0; ni < 8; ni++) acc[mi][ni] = (f32x4){0.f, 0.f, 0.f, 0.f};

    auto stageB = [&](int sidx) {
        const unsigned short* wsrc = Wp + (size_t)sidx * 8192;
        unsigned short* Bd = &Bs[sidx & 1][0];
#pragma unroll
        for (int i = 0; i < 4; ++i) {
            __builtin_amdgcn_global_load_lds(
                (const GAS void*)(wsrc + (size_t)(i * 256 + t) * 8),
                (LAS void*)(Bd + (size_t)(i * 256 + wave * 64) * 8), 16, 0, 0);
        }
    };
    auto loadA = [&](int sidx, uint4* aR) {
        const int k1 = sidx >> 1, h1 = sidx & 1;
#pragma unroll
        for (int mi = 0; mi < 4; mi++) {
            int srow = nbrS[(wave * 64 + mi * 16 + l15) * 27 + k1];
            const unsigned short* base = X + (size_t)srow * 128 + h1 * 64 + l4 * 8;
            aR[mi * 2 + 0] = *reinterpret_cast<const uint4*>(base);        // kk=0
            aR[mi * 2 + 1] = *reinterpret_cast<const uint4*>(base + 32);   // kk=1
        }
    };

    uint4 aP[8], aQ[8];
    __syncthreads();           // nbrS ready
    loadA(0, aP);
    stageB(0);
    __syncthreads();           // Bs[0] landed

#define STEP(SIDX, ACUR, ANEXT)                                                          \
    {                                                                                    \
        if ((SIDX) < 53) { loadA((SIDX) + 1, ANEXT); stageB((SIDX) + 1); }               \
        _Pragma("unroll")                                                                \
        for (int kk = 0; kk < 2; ++kk) {                                                 \
            bf16x8 a[4], b[8];                                                           \
            _Pragma("unroll")                                                            \
            for (int mi = 0; mi < 4; mi++)                                               \
                a[mi] = __builtin_bit_cast(bf16x8, ACUR[mi * 2 + kk]);                   \
            _Pragma("unroll")                                                            \
            for (int ni = 0; ni < 8; ni++) {                                             \
                int co = ni * 16 + l15;                                                  \
                b[ni] = *reinterpret_cast<const bf16x8*>(                                \
                    &Bs[(SIDX) & 1][co * 64 + (((kk * 4 + l4) ^ (co & 7)) * 8)]);        \
            }                                                                            \
            _Pragma("unroll")                                                            \
            for (int mi = 0; mi < 4; mi++)                                               \
                _Pragma("unroll")                                                        \
                for (int ni = 0; ni < 8; ni++)                                           \
                    acc[mi][ni] = __builtin_amdgcn_mfma_f32_16x16x32_bf16(               \
                        a[mi], b[ni], acc[mi][ni], 0, 0, 0);                             \
        }                                                                                \
        __syncthreads();                                                                 \
    }

    for (int s = 0; s < 54; s += 2) {
        STEP(s, aP, aQ);
        STEP(s + 1, aQ, aP);
    }
#undef STEP

    // ---- epilogue: store + fused instance-norm stats ----
    const int b_lo = bidx[n0];
    const int b_hi = bidx[n0 + 255];
    const bool split = (b_hi != b_lo);

    float ps0[8], ps1[8], pq0[8], pq1[8];
#pragma unroll
    for (int ni = 0; ni < 8; ni++) { ps0[ni] = 0.f; ps1[ni] = 0.f; pq0[ni] = 0.f; pq1[ni] = 0.f; }
#pragma unroll
    for (int mi = 0; mi < 4; mi++) {
#pragma unroll
        for (int j = 0; j < 4; j++) {
            int rowm = wave * 64 + mi * 16 + l4 * 4 + j;
            bool hi = split && (bidx[n0 + rowm] != b_lo);
#pragma unroll
            for (int ni = 0; ni < 8; ni++) {
                float v = acc[mi][ni][j];
                float v1 = hi ? v : 0.f;
                float v0 = v - v1;
                ps0[ni] += v0; pq0[ni] += v0 * v;
                ps1[ni] += v1; pq1[ni] += v1 * v;
                storeval(out + (size_t)(n0 + rowm) * 128 + ni * 16 + l15, v);
            }
        }
    }
#pragma unroll
    for (int ni = 0; ni < 8; ni++) {
        int col = ni * 16 + l15;
        atomicAdd(&ssum[0][col], ps0[ni]);
        atomicAdd(&ssq[0][col], pq0[ni]);
        if (split) {
            atomicAdd(&ssum[1][col], ps1[ni]);
            atomicAdd(&ssq[1][col], pq1[ni]);
        }
    }
    if (split) {
        bool hi2 = (bidx[n0 + t] != b_lo);
        unsigned long long m = __ballot(hi2);
        if (lane == 0) atomicAdd(&shi, (float)__popcll(m));
    }
    __syncthreads();
    {
        int slot = t >> 7, c = t & 127;
        if (slot == 0 || split) {
            int b = slot ? b_hi : b_lo;
            atomicAdd(&gsum[b * 128 + c], ssum[slot][c]);
            atomicAdd(&gsq[b * 128 + c], ssq[slot][c]);
        }
        if (t == 0) {
            float nhi = shi;
            atomicAdd(&gcnt[b_lo], 256.f - nhi);
            if (split) atomicAdd(&gcnt[b_hi], nhi);
        }
    }
}

// ---------------------------------------------------------------------------
// apply1: y = elu( norm(out1) * (1+scale) + shift )  -> bf16
// ---------------------------------------------------------------------------
__global__ void apply1_kernel(const unsigned short* __restrict__ o1, const int* __restrict__ bidx,
                              const float* __restrict__ gsum, const float* __restrict__ gsq,
                              const float* __restrict__ gcnt, const float* __restrict__ e,
                              unsigned short* __restrict__ y, int N) {
    int idx = blockIdx.x * 256 + threadIdx.x;
    int n = idx >> 5;
    if (n >= N) return;
    int c0 = (idx & 31) << 2;
    int b = bidx[n];
    float icnt = 1.0f / fmaxf(gcnt[b], 1.0f);
    ushort4 vv = *reinterpret_cast<const ushort4*>(o1 + (size_t)n * 128 + c0);
    const unsigned short* pv = reinterpret_cast<const unsigned short*>(&vv);
    unsigned short res[4];
#pragma unroll
    for (int j = 0; j < 4; j++) {
        int c = c0 + j;
        float m = gsum[b * 128 + c] * icnt;
        float var = gsq[b * 128 + c] * icnt - m * m;
        float rs = rsqrtf(fmaxf(var, 0.f) + 1e-6f);
        float xn = (bf2f(pv[j]) - m) * rs;
        float sc = e[b * 256 + c];
        float sh = e[b * 256 + 128 + c];
        float tt = xn * (1.0f + sc) + sh;
        float r = tt > 0.f ? tt : expm1f(tt);
        res[j] = f2bf(r);
    }
    *reinterpret_cast<ushort4*>(y + (size_t)n * 128 + c0) = *reinterpret_cast<ushort4*>(res);
}

// ---------------------------------------------------------------------------
// apply2: out = elu( norm(out2) + x_feats )  -> f32, in place on d_out
// ---------------------------------------------------------------------------
__global__ void apply2_kernel(float* __restrict__ o2, const float* __restrict__ xf,
                              const int* __restrict__ bidx, const float* __restrict__ gsum,
                              const float* __restrict__ gsq, const float* __restrict__ gcnt, int N) {
    int idx = blockIdx.x * 256 + threadIdx.x;
    int n = idx >> 5;
    if (n >= N) return;
    int c0 = (idx & 31) << 2;
    int b = bidx[n];
    float icnt = 1.0f / fmaxf(gcnt[b], 1.0f);
    float4 v = *reinterpret_cast<const float4*>(o2 + (size_t)n * 128 + c0);
    float4 xv = *reinterpret_cast<const float4*>(xf + (size_t)n * 128 + c0);
    const float* pv = reinterpret_cast<const float*>(&v);
    const float* px = reinterpret_cast<const float*>(&xv);
    float res[4];
#pragma unroll
    for (int j = 0; j < 4; j++) {
        int c = c0 + j;
        float m = gsum[b * 128 + c] * icnt;
        float var = gsq[b * 128 + c] * icnt - m * m;
        float rs = rsqrtf(fmaxf(var, 0.f) + 1e-6f);
        float zn = (pv[j] - m) * rs;
        float r2 = zn + px[j];
        res[j] = r2 > 0.f ? r2 : expm1f(r2);
    }
    *reinterpret_cast<float4*>(o2 + (size_t)n * 128 + c0) =
        *reinterpret_cast<float4*>(res);
}

// ---------------------------------------------------------------------------
extern "C" void kernel_launch(void* const* d_in, const int* in_sizes, int n_in,
                              void* d_out, int out_size, void* d_ws, size_t ws_size,
                              hipStream_t stream) {
    const float* x    = (const float*)d_in[0];
    const float* emb  = (const float*)d_in[1];
    const float* W1   = (const float*)d_in[2];
    const float* W2   = (const float*)d_in[3];
    const float* Wt   = (const float*)d_in[4];
    const float* bt   = (const float*)d_in[5];
    const int* bidx   = (const int*)d_in[6];
    const int* nbr    = (const int*)d_in[7];
    float* out        = (float*)d_out;
    const int N = in_sizes[0] / 128;

    char* ws = (char*)d_ws;
    unsigned short* xb  = (unsigned short*)ws;                          // N*128 bf16 (reused as y)
    unsigned short* o1b = (unsigned short*)(ws + (size_t)N * 256);      // N*128 bf16
    unsigned short* w1p = (unsigned short*)(ws + (size_t)N * 512);      // 27*16384 bf16
    unsigned short* w2p = w1p + 27 * 16384;
    float* e    = (float*)(w2p + 27 * 16384);                           // 8*256
    float* st   = e + 2048;
    float* sum1 = st;
    float* sq1  = st + 1024;
    float* cnt1 = st + 2048;
    float* sum2 = st + 2056;
    float* sq2  = st + 3080;
    float* cnt2 = st + 4104;

    hipMemsetAsync(st, 0, 4112 * sizeof(float), stream);

    int total = N * 128;
    prep_x_kernel<<<(total / 4 + 255) / 256, 256, 0, stream>>>(x, xb, total);
    prep_w_kernel<<<27 * 64, 256, 0, stream>>>(W1, w1p);
    prep_w_kernel<<<27 * 64, 256, 0, stream>>>(W2, w2p);
    film_kernel<<<512, 256, 0, stream>>>(emb, Wt, bt, e);

    conv_kernel<unsigned short><<<N / 256, 256, 0, stream>>>(xb, nbr, w1p, o1b, bidx, sum1, sq1, cnt1, N);
    apply1_kernel<<<(N * 32 + 255) / 256, 256, 0, stream>>>(o1b, bidx, sum1, sq1, cnt1, e, xb, N);

    conv_kernel<float><<<N / 256, 256, 0, stream>>>(xb, nbr, w2p, out, bidx, sum2, sq2, cnt2, N);
    apply2_kernel<<<(N * 32 + 255) / 256, 256, 0, stream>>>(out, x, bidx, sum2, sq2, cnt2, N);
}